// Round 1
// baseline (719.973 us; speedup 1.0000x reference)
//
#include <hip/hip_runtime.h>

// B-spline 3D field evaluation, 2M points, 128^3 x 3 f32 control grid.
// Baseline strategy:
//  - 1 thread / point, fully unrolled 4x4 (l,m) loop.
//  - per (l,m): 3x float4 loads covering the 12 contiguous floats of the
//    4 z-taps (phi layout [x][y][z][c], c innermost, C=3 -> 48B run).
//  - z-clamp handled by shifting z-weights once per point (iz==125 case),
//    so every load is the contiguous fast path. x/y clamped indices hoisted.
//  - arithmetic mirrors reference: u = (x - ox - dx)/dx with fp32 divide.

__device__ __forceinline__ void bspline_w(float u, float& w0, float& w1,
                                          float& w2, float& w3) {
    const float u2 = u * u;
    const float u3 = u2 * u;
    const float t  = 1.0f - u;
    w0 = t * t * t * (1.0f / 6.0f);
    w1 = (3.0f * u3 - 6.0f * u2 + 4.0f) * (1.0f / 6.0f);
    w2 = (-3.0f * u3 + 3.0f * u2 + 3.0f * u + 1.0f) * (1.0f / 6.0f);
    w3 = u3 * (1.0f / 6.0f);
}

__global__ __launch_bounds__(256) void bspline3d_kernel(
    const float* __restrict__ xs, const float* __restrict__ ys,
    const float* __restrict__ zs, const float* __restrict__ phi,
    float* __restrict__ out, int n) {
    const int i = blockIdx.x * blockDim.x + threadIdx.x;
    if (i >= n) return;

    // spacing/origin exactly as reference: dx = 2/(128-3), ox = -1 - dx
    const float dx = 2.0f / 125.0f;
    const float ox = -1.0f - dx;

    float u = (xs[i] - ox - dx) / dx;
    float v = (ys[i] - ox - dx) / dx;
    float w = (zs[i] - ox - dx) / dx;

    const float fu = floorf(u), fv = floorf(v), fw = floorf(w);
    const int ix = (int)fu, iy = (int)fv, iz = (int)fw;
    u -= fu; v -= fv; w -= fw;

    float wu[4], wv[4], wz[4];
    bspline_w(u, wu[0], wu[1], wu[2], wu[3]);
    bspline_w(v, wv[0], wv[1], wv[2], wv[3]);
    bspline_w(w, wz[0], wz[1], wz[2], wz[3]);

    // z clamp via weight shift: load base izb = clamp(iz, 0, 124) is always a
    // contiguous 12-float run covering z = izb..izb+3. If iz==125 the needed
    // taps are z=125,126,127,127 -> weights shift down one slot, last merges.
    int izb = iz < 0 ? 0 : iz;
    const bool sh = izb > 124;
    if (sh) izb = 124;
    const float zw0 = sh ? 0.0f : wz[0];
    const float zw1 = sh ? wz[0] : wz[1];
    const float zw2 = sh ? wz[1] : wz[2];
    const float zw3 = sh ? (wz[2] + wz[3]) : wz[3];

    // hoisted clamped x/y indices
    int xi[4], yi[4];
#pragma unroll
    for (int l = 0; l < 4; ++l) {
        int t = ix + l;
        xi[l] = min(max(t, 0), 127);
        t = iy + l;
        yi[l] = min(max(t, 0), 127);
    }

    const float* pz = phi + izb * 3;  // base includes z offset

    float acc0 = 0.0f, acc1 = 0.0f, acc2 = 0.0f;
#pragma unroll
    for (int l = 0; l < 4; ++l) {
        const int rowx = xi[l] << 7;  // xi*128
#pragma unroll
        for (int m = 0; m < 4; ++m) {
            // element offset (xi*128 + yi) * 128 * 3
            const float* p = pz + (rowx + yi[m]) * 384;
            const float4 a = *reinterpret_cast<const float4*>(p);
            const float4 b = *reinterpret_cast<const float4*>(p + 4);
            const float4 c = *reinterpret_cast<const float4*>(p + 8);
            const float wm = wu[l] * wv[m];
            const float c0 = wm * zw0;
            const float c1 = wm * zw1;
            const float c2 = wm * zw2;
            const float c3 = wm * zw3;
            acc0 = fmaf(c0, a.x, acc0);
            acc1 = fmaf(c0, a.y, acc1);
            acc2 = fmaf(c0, a.z, acc2);
            acc0 = fmaf(c1, a.w, acc0);
            acc1 = fmaf(c1, b.x, acc1);
            acc2 = fmaf(c1, b.y, acc2);
            acc0 = fmaf(c2, b.z, acc0);
            acc1 = fmaf(c2, b.w, acc1);
            acc2 = fmaf(c2, c.x, acc2);
            acc0 = fmaf(c3, c.y, acc0);
            acc1 = fmaf(c3, c.z, acc1);
            acc2 = fmaf(c3, c.w, acc2);
        }
    }

    float* o = out + 3 * (size_t)i;
    o[0] = acc0;
    o[1] = acc1;
    o[2] = acc2;
}

extern "C" void kernel_launch(void* const* d_in, const int* in_sizes, int n_in,
                              void* d_out, int out_size, void* d_ws,
                              size_t ws_size, hipStream_t stream) {
    const float* xs  = (const float*)d_in[0];
    const float* ys  = (const float*)d_in[1];
    const float* zs  = (const float*)d_in[2];
    const float* phi = (const float*)d_in[3];
    float* out = (float*)d_out;
    const int n = in_sizes[0];

    const int block = 256;
    const int grid = (n + block - 1) / block;
    bspline3d_kernel<<<grid, block, 0, stream>>>(xs, ys, zs, phi, out, n);
}

// Round 2
// 234.277 us; speedup vs baseline: 3.0732x; 3.0732x over previous
//
#include <hip/hip_runtime.h>

// B-spline 3D field, 2M points, 128^3 x 3 f32 grid.
// Round 2: counting-sort points into 16^3 spatial bins (8^3 cells each),
// then evaluate one bin per block with the bin's 11^3 phi brick staged in
// LDS (float4-padded -> all taps are ds_read_b128). Removes the 2.35 GB
// of random L2-miss gather traffic seen in round 1.

#define NBINS 4096   // 16x16x16
#define NBLK  256    // histogram/scatter blocks (must match between passes)
#define BRICK 1331   // 11^3 grid points per bin brick

__device__ __forceinline__ void bspline_w(float u, float& w0, float& w1,
                                          float& w2, float& w3) {
    const float u2 = u * u;
    const float u3 = u2 * u;
    const float t  = 1.0f - u;
    w0 = t * t * t * (1.0f / 6.0f);
    w1 = (3.0f * u3 - 6.0f * u2 + 4.0f) * (1.0f / 6.0f);
    w2 = (-3.0f * u3 + 3.0f * u2 + 3.0f * u + 1.0f) * (1.0f / 6.0f);
    w3 = u3 * (1.0f / 6.0f);
}

// cell indices from coords; must be identical fp ops in every pass
__device__ __forceinline__ void cell_ids(float x, float y, float z,
                                         int& ix, int& iy, int& iz) {
    const float dx = 2.0f / 125.0f;
    const float ox = -1.0f - dx;
    const float u = (x - ox - dx) / dx;
    const float v = (y - ox - dx) / dx;
    const float w = (z - ox - dx) / dx;
    ix = (int)floorf(u);
    iy = (int)floorf(v);
    iz = (int)floorf(w);
}

__device__ __forceinline__ int point_bin(float x, float y, float z) {
    int ix, iy, iz;
    cell_ids(x, y, z, ix, iy, iz);
    const int bx = min(max(ix, 0), 127) >> 3;
    const int by = min(max(iy, 0), 127) >> 3;
    const int bz = min(max(iz, 0), 127) >> 3;
    return (bx << 8) | (by << 4) | bz;
}

// ---- pass A: per-block histograms ----
__global__ __launch_bounds__(256) void hist_kernel(
    const float* __restrict__ xs, const float* __restrict__ ys,
    const float* __restrict__ zs, unsigned* __restrict__ hist,
    int n, int chunk) {
    __shared__ unsigned h[NBINS];
    for (int j = threadIdx.x; j < NBINS; j += 256) h[j] = 0;
    __syncthreads();
    const int b = blockIdx.x;
    const int lo = b * chunk;
    const int hi = min(n, lo + chunk);
    for (int i = lo + threadIdx.x; i < hi; i += 256) {
        atomicAdd(&h[point_bin(xs[i], ys[i], zs[i])], 1u);
    }
    __syncthreads();
    for (int j = threadIdx.x; j < NBINS; j += 256) hist[b * NBINS + j] = h[j];
}

// ---- pass B1: per-bin totals ----
__global__ __launch_bounds__(256) void totals_kernel(
    const unsigned* __restrict__ hist, unsigned* __restrict__ total) {
    const int j = blockIdx.x * 256 + threadIdx.x;
    unsigned s = 0;
    for (int b = 0; b < NBLK; ++b) s += hist[b * NBINS + j];
    total[j] = s;
}

// ---- pass B2: exclusive scan of totals -> binbase (1 block, 1024 thr) ----
__global__ __launch_bounds__(1024) void scan_kernel(
    const unsigned* __restrict__ total, unsigned* __restrict__ binbase) {
    __shared__ unsigned sdata[1024];
    const int t = threadIdx.x;
    const unsigned v0 = total[4 * t + 0];
    const unsigned v1 = total[4 * t + 1];
    const unsigned v2 = total[4 * t + 2];
    const unsigned v3 = total[4 * t + 3];
    sdata[t] = v0 + v1 + v2 + v3;
    __syncthreads();
    for (int off = 1; off < 1024; off <<= 1) {
        unsigned x = (t >= off) ? sdata[t - off] : 0u;
        __syncthreads();
        sdata[t] += x;
        __syncthreads();
    }
    const unsigned ex = (t > 0) ? sdata[t - 1] : 0u;
    binbase[4 * t + 0] = ex;
    binbase[4 * t + 1] = ex + v0;
    binbase[4 * t + 2] = ex + v0 + v1;
    binbase[4 * t + 3] = ex + v0 + v1 + v2;
}

// ---- pass B3: turn hist[b][j] into scatter start offsets ----
__global__ __launch_bounds__(256) void fixup_kernel(
    unsigned* __restrict__ hist, const unsigned* __restrict__ binbase) {
    const int j = blockIdx.x * 256 + threadIdx.x;
    unsigned run = binbase[j];
    for (int b = 0; b < NBLK; ++b) {
        const unsigned c = hist[b * NBINS + j];
        hist[b * NBINS + j] = run;
        run += c;
    }
}

// ---- pass C: scatter (x,y,z,idx) records into bin-sorted order ----
__global__ __launch_bounds__(256) void scatter_kernel(
    const float* __restrict__ xs, const float* __restrict__ ys,
    const float* __restrict__ zs, const unsigned* __restrict__ hist,
    float4* __restrict__ rec, int n, int chunk) {
    __shared__ unsigned off[NBINS];
    const int b = blockIdx.x;
    for (int j = threadIdx.x; j < NBINS; j += 256) off[j] = hist[b * NBINS + j];
    __syncthreads();
    const int lo = b * chunk;
    const int hi = min(n, lo + chunk);
    for (int i = lo + threadIdx.x; i < hi; i += 256) {
        const float x = xs[i], y = ys[i], z = zs[i];
        const unsigned p = atomicAdd(&off[point_bin(x, y, z)], 1u);
        rec[p] = make_float4(x, y, z, __int_as_float(i));
    }
}

// ---- pass D: evaluate, one block per bin, phi brick in LDS ----
__global__ __launch_bounds__(256) void eval_kernel(
    const float4* __restrict__ rec, const unsigned* __restrict__ binbase,
    const unsigned* __restrict__ total, const float* __restrict__ phi,
    float* __restrict__ out) {
    const int bin = blockIdx.x;
    const unsigned cnt = total[bin];
    if (cnt == 0) return;
    const unsigned start = binbase[bin];

    const int gx0 = ((bin >> 8) & 15) << 3;
    const int gy0 = ((bin >> 4) & 15) << 3;
    const int gz0 = (bin & 15) << 3;

    __shared__ float4 brick[BRICK];
    for (int p = threadIdx.x; p < BRICK; p += 256) {
        const int lx = p / 121;
        const int r  = p - lx * 121;
        const int ly = r / 11;
        const int lz = r - ly * 11;
        const int gx = min(gx0 + lx, 127);
        const int gy = min(gy0 + ly, 127);
        const int gz = min(gz0 + lz, 127);
        const float* s = phi + (size_t)((gx * 128 + gy) * 128 + gz) * 3;
        brick[p] = make_float4(s[0], s[1], s[2], 0.0f);
    }
    __syncthreads();

    for (unsigned k = start + threadIdx.x; k < start + cnt; k += 256) {
        const float4 r4 = rec[k];
        const int idx = __float_as_int(r4.w);

        int ix, iy, iz;
        cell_ids(r4.x, r4.y, r4.z, ix, iy, iz);
        const float dx = 2.0f / 125.0f;
        const float ox = -1.0f - dx;
        float u = (r4.x - ox - dx) / dx - floorf((r4.x - ox - dx) / dx);
        float v = (r4.y - ox - dx) / dx - floorf((r4.y - ox - dx) / dx);
        float w = (r4.z - ox - dx) / dx - floorf((r4.z - ox - dx) / dx);

        float wu[4], wv[4], wz[4];
        bspline_w(u, wu[0], wu[1], wu[2], wu[3]);
        bspline_w(v, wv[0], wv[1], wv[2], wv[3]);
        bspline_w(w, wz[0], wz[1], wz[2], wz[3]);

        // z clamp via weight shift (same semantics as round-1 kernel)
        int izb = iz < 0 ? 0 : iz;
        const bool sh = izb > 124;
        if (sh) izb = 124;
        const float zw0 = sh ? 0.0f : wz[0];
        const float zw1 = sh ? wz[0] : wz[1];
        const float zw2 = sh ? wz[1] : wz[2];
        const float zw3 = sh ? (wz[2] + wz[3]) : wz[3];
        const int lzb = izb - gz0;  // in [0,7]

        int lxi[4], lyi[4];
#pragma unroll
        for (int l = 0; l < 4; ++l) {
            lxi[l] = min(max(ix + l, 0), 127) - gx0;  // in [0,10]
            lyi[l] = min(max(iy + l, 0), 127) - gy0;
        }

        float acc0 = 0.0f, acc1 = 0.0f, acc2 = 0.0f;
#pragma unroll
        for (int l = 0; l < 4; ++l) {
            const int rowx = lxi[l] * 11;
#pragma unroll
            for (int m = 0; m < 4; ++m) {
                const float4* p0 = &brick[(rowx + lyi[m]) * 11 + lzb];
                const float wm = wu[l] * wv[m];
                const float c0 = wm * zw0;
                const float c1 = wm * zw1;
                const float c2 = wm * zw2;
                const float c3 = wm * zw3;
                const float4 a = p0[0];
                const float4 b = p0[1];
                const float4 c = p0[2];
                const float d = c3;
                const float4 e = p0[3];
                acc0 = fmaf(c0, a.x, acc0);
                acc1 = fmaf(c0, a.y, acc1);
                acc2 = fmaf(c0, a.z, acc2);
                acc0 = fmaf(c1, b.x, acc0);
                acc1 = fmaf(c1, b.y, acc1);
                acc2 = fmaf(c1, b.z, acc2);
                acc0 = fmaf(c2, c.x, acc0);
                acc1 = fmaf(c2, c.y, acc1);
                acc2 = fmaf(c2, c.z, acc2);
                acc0 = fmaf(d, e.x, acc0);
                acc1 = fmaf(d, e.y, acc1);
                acc2 = fmaf(d, e.z, acc2);
            }
        }
        float* o = out + 3 * (size_t)idx;
        o[0] = acc0;
        o[1] = acc1;
        o[2] = acc2;
    }
}

// ---- round-1 direct kernel as fallback if ws is too small ----
__global__ __launch_bounds__(256) void bspline3d_direct(
    const float* __restrict__ xs, const float* __restrict__ ys,
    const float* __restrict__ zs, const float* __restrict__ phi,
    float* __restrict__ out, int n) {
    const int i = blockIdx.x * blockDim.x + threadIdx.x;
    if (i >= n) return;
    const float dx = 2.0f / 125.0f;
    const float ox = -1.0f - dx;
    float u = (xs[i] - ox - dx) / dx;
    float v = (ys[i] - ox - dx) / dx;
    float w = (zs[i] - ox - dx) / dx;
    const float fu = floorf(u), fv = floorf(v), fw = floorf(w);
    const int ix = (int)fu, iy = (int)fv, iz = (int)fw;
    u -= fu; v -= fv; w -= fw;
    float wu[4], wv[4], wz[4];
    bspline_w(u, wu[0], wu[1], wu[2], wu[3]);
    bspline_w(v, wv[0], wv[1], wv[2], wv[3]);
    bspline_w(w, wz[0], wz[1], wz[2], wz[3]);
    int izb = iz < 0 ? 0 : iz;
    const bool sh = izb > 124;
    if (sh) izb = 124;
    const float zw0 = sh ? 0.0f : wz[0];
    const float zw1 = sh ? wz[0] : wz[1];
    const float zw2 = sh ? wz[1] : wz[2];
    const float zw3 = sh ? (wz[2] + wz[3]) : wz[3];
    int xi[4], yi[4];
#pragma unroll
    for (int l = 0; l < 4; ++l) {
        xi[l] = min(max(ix + l, 0), 127);
        yi[l] = min(max(iy + l, 0), 127);
    }
    const float* pz = phi + izb * 3;
    float acc0 = 0.0f, acc1 = 0.0f, acc2 = 0.0f;
#pragma unroll
    for (int l = 0; l < 4; ++l) {
        const int rowx = xi[l] << 7;
#pragma unroll
        for (int m = 0; m < 4; ++m) {
            const float* p = pz + (rowx + yi[m]) * 384;
            const float4 a = *reinterpret_cast<const float4*>(p);
            const float4 b = *reinterpret_cast<const float4*>(p + 4);
            const float4 c = *reinterpret_cast<const float4*>(p + 8);
            const float wm = wu[l] * wv[m];
            const float c0 = wm * zw0, c1 = wm * zw1, c2 = wm * zw2, c3 = wm * zw3;
            acc0 = fmaf(c0, a.x, acc0); acc1 = fmaf(c0, a.y, acc1); acc2 = fmaf(c0, a.z, acc2);
            acc0 = fmaf(c1, a.w, acc0); acc1 = fmaf(c1, b.x, acc1); acc2 = fmaf(c1, b.y, acc2);
            acc0 = fmaf(c2, b.z, acc0); acc1 = fmaf(c2, b.w, acc1); acc2 = fmaf(c2, c.x, acc2);
            acc0 = fmaf(c3, c.y, acc0); acc1 = fmaf(c3, c.z, acc1); acc2 = fmaf(c3, c.w, acc2);
        }
    }
    float* o = out + 3 * (size_t)i;
    o[0] = acc0; o[1] = acc1; o[2] = acc2;
}

extern "C" void kernel_launch(void* const* d_in, const int* in_sizes, int n_in,
                              void* d_out, int out_size, void* d_ws,
                              size_t ws_size, hipStream_t stream) {
    const float* xs  = (const float*)d_in[0];
    const float* ys  = (const float*)d_in[1];
    const float* zs  = (const float*)d_in[2];
    const float* phi = (const float*)d_in[3];
    float* out = (float*)d_out;
    const int n = in_sizes[0];

    // ws layout
    const size_t hist_off = 0;                                  // u32[256][4096]
    const size_t total_off = hist_off + (size_t)NBLK * NBINS * 4;  // u32[4096]
    const size_t base_off  = total_off + NBINS * 4;                // u32[4096]
    const size_t rec_off   = base_off + NBINS * 4;                 // float4[n]
    const size_t need = rec_off + (size_t)n * 16;

    if (ws_size < need) {
        const int block = 256;
        bspline3d_direct<<<(n + block - 1) / block, block, 0, stream>>>(
            xs, ys, zs, phi, out, n);
        return;
    }

    unsigned* hist    = (unsigned*)((char*)d_ws + hist_off);
    unsigned* total   = (unsigned*)((char*)d_ws + total_off);
    unsigned* binbase = (unsigned*)((char*)d_ws + base_off);
    float4*   rec     = (float4*)((char*)d_ws + rec_off);

    const int chunk = (n + NBLK - 1) / NBLK;

    hist_kernel<<<NBLK, 256, 0, stream>>>(xs, ys, zs, hist, n, chunk);
    totals_kernel<<<NBINS / 256, 256, 0, stream>>>(hist, total);
    scan_kernel<<<1, 1024, 0, stream>>>(total, binbase);
    fixup_kernel<<<NBINS / 256, 256, 0, stream>>>(hist, binbase);
    scatter_kernel<<<NBLK, 256, 0, stream>>>(xs, ys, zs, hist, rec, n, chunk);
    eval_kernel<<<NBINS, 256, 0, stream>>>(rec, binbase, total, phi, out);
}